// Round 1
// 329.584 us; speedup vs baseline: 1.0341x; 1.0341x over previous
//
#include <hip/hip_runtime.h>
#include <math.h>

#define SEQ      8192
#define NTHREADS 256
#define VPT      32           // values per thread per row
#define F4PT     8            // float4 per thread per row

__device__ __forceinline__ float wave_sum(float x) {
    #pragma unroll
    for (int off = 32; off > 0; off >>= 1)
        x += __shfl_xor(x, off, 64);
    return x;
}

// One row per 256-thread block (4 waves). Payload = 32 floats/thread -> VGPR<=64
// so 8 waves/SIMD can be resident (launch_bounds pins it). All per-iteration
// work that does not depend on the reduction result (u *= 1/0.7 rescale, the
// t=7 e-domain conversion) is issued between the LDS write and the barrier so
// it hides in the sync shadow.
__global__ __launch_bounds__(NTHREADS, 8) void normalizer_kernel(
        const float* __restrict__ score,
        const int*   __restrict__ mask,
        float*       __restrict__ out)
{
    const int row  = blockIdx.x;
    const int tid  = threadIdx.x;
    const int wid  = tid >> 6;
    const int lane = tid & 63;

    constexpr double L2E = 1.4426950408889634;            // log2(e)
    constexpr double TH7 = 4.0*0.7*0.7*0.7*0.7*0.7*0.7*0.7;  // theta at t=7 (0.32942 > 0.3)
    const float cu0 = (float)(L2E / 4.0);   // score -> u = score*log2e/theta0
    const float r07 = (float)(1.0 / 0.7);   // theta_t / theta_{t+1}
    const float ce  = (float)(TH7 / 0.3);   // u7 -> w-domain scale (for exp2)

    const float4* __restrict__ s4 = (const float4*)(score + (size_t)row * SEQ);
    const int4*   __restrict__ m4 = (const int4*)(mask  + (size_t)row * SEQ);

    // u_t = score * log2e / theta_t, masked -> -inf (exp2(-inf)=0 handles all)
    float u[VPT];
    int cnt = 0;
    #pragma unroll
    for (int j = 0; j < F4PT; ++j) {
        float4 s = s4[j * NTHREADS + tid];
        int4   m = m4[j * NTHREADS + tid];
        u[4*j+0] = m.x ? s.x * cu0 : -INFINITY;
        u[4*j+1] = m.y ? s.y * cu0 : -INFINITY;
        u[4*j+2] = m.z ? s.z * cu0 : -INFINITY;
        u[4*j+3] = m.w ? s.w * cu0 : -INFINITY;
        cnt += (m.x != 0) + (m.y != 0) + (m.z != 0) + (m.w != 0);
    }

    __shared__ float redc[4];
    __shared__ float red[2][4];   // double-buffered: one barrier per iteration

    // ---- fused: mask count + t=0 sum (NA = +inf at t=0, so no clamp, no k) ----
    float a0 = 0.f, a1 = 0.f;
    #pragma unroll
    for (int j = 0; j < VPT; j += 2) {
        a0 += __builtin_amdgcn_exp2f(u[j]);
        a1 += __builtin_amdgcn_exp2f(u[j+1]);
    }
    float pc = wave_sum((float)cnt);
    float ps = wave_sum(a0 + a1);
    if (lane == 0) { redc[wid] = pc; red[0][wid] = ps; }
    #pragma unroll
    for (int j = 0; j < VPT; ++j) u[j] *= r07;   // prep t=1 in sync shadow
    __syncthreads();
    const float k   = 0.1f * (redc[0] + redc[1] + redc[2] + redc[3]);
    const float l2k = __builtin_amdgcn_logf(k);  // v_log_f32 = log2
    const float rk  = 1.0f / k;
    float s_ = red[0][0] + red[0][1] + red[0][2] + red[0][3];
    // NAcp for iter t+1 = (log2 s_t - log2 k) * theta_t/theta_{t+1} = (..)*(1/0.7)
    float NAcp = (__builtin_amdgcn_logf(s_ + 1e-20f) - l2k) * r07;

    // ---- t = 1..6: identical bodies, rolled ----
    for (int t = 1; t < 7; ++t) {
        a0 = 0.f; a1 = 0.f;
        #pragma unroll
        for (int j = 0; j < VPT; j += 2) {
            a0 += __builtin_amdgcn_exp2f(fminf(u[j],   NAcp));
            a1 += __builtin_amdgcn_exp2f(fminf(u[j+1], NAcp));
        }
        float pa = wave_sum(a0 + a1);
        if (lane == 0) red[t & 1][wid] = pa;
        #pragma unroll
        for (int j = 0; j < VPT; ++j) u[j] *= r07;  // independent: sync shadow
        __syncthreads();
        s_ = red[t & 1][0] + red[t & 1][1] + red[t & 1][2] + red[t & 1][3];
        NAcp = (__builtin_amdgcn_logf(s_ + 1e-20f) - l2k) * r07;
    }

    // ---- t = 7: last exp step; convert u -> e = exp2(w) in the sync shadow ----
    {
        a0 = 0.f; a1 = 0.f;
        #pragma unroll
        for (int j = 0; j < VPT; j += 2) {
            a0 += __builtin_amdgcn_exp2f(fminf(u[j],   NAcp));
            a1 += __builtin_amdgcn_exp2f(fminf(u[j+1], NAcp));
        }
        float pa = wave_sum(a0 + a1);
        if (lane == 0) red[1][wid] = pa;           // 7 & 1
        #pragma unroll
        for (int j = 0; j < VPT; ++j)
            u[j] = __builtin_amdgcn_exp2f(u[j] * ce);   // e-domain, sync shadow
        __syncthreads();
        s_ = red[1][0] + red[1][1] + red[1][2] + red[1][3];
    }
    // eNA = exp2(NA_7) = exp2((log2 s7 - log2 k) * theta7/0.3)
    float eNA = __builtin_amdgcn_exp2f((__builtin_amdgcn_logf(s_ + 1e-20f) - l2k) * ce);

    // ---- t = 8..19: theta = 0.3 clamped; s = sum(min(e, eNA)); eNA' = s/k ----
    for (int t = 8; t < 20; ++t) {
        a0 = 0.f; a1 = 0.f;
        #pragma unroll
        for (int j = 0; j < VPT; j += 2) {
            a0 += fminf(u[j],   eNA);
            a1 += fminf(u[j+1], eNA);
        }
        float pa = wave_sum(a0 + a1);
        if (lane == 0) red[t & 1][wid] = pa;
        __syncthreads();
        s_ = red[t & 1][0] + red[t & 1][1] + red[t & 1][2] + red[t & 1][3];
        eNA = (s_ + 1e-20f) * rk;
    }

    // gamma = min(e, eNA) / eNA.  Masked: e = 0 -> 0.
    const float ra = 1.0f / eNA;
    float4* __restrict__ o4 = (float4*)(out + (size_t)row * SEQ);
    #pragma unroll
    for (int j = 0; j < F4PT; ++j) {
        float4 g;
        g.x = fminf(u[4*j+0], eNA) * ra;
        g.y = fminf(u[4*j+1], eNA) * ra;
        g.z = fminf(u[4*j+2], eNA) * ra;
        g.w = fminf(u[4*j+3], eNA) * ra;
        o4[j * NTHREADS + tid] = g;
    }
}

extern "C" void kernel_launch(void* const* d_in, const int* in_sizes, int n_in,
                              void* d_out, int out_size, void* d_ws, size_t ws_size,
                              hipStream_t stream) {
    const float* score = (const float*)d_in[0];
    const int*   mask  = (const int*)d_in[1];
    float*       out   = (float*)d_out;
    const int rows = in_sizes[0] / SEQ;          // 4096
    normalizer_kernel<<<rows, NTHREADS, 0, stream>>>(score, mask, out);
}

// Round 2
// 325.095 us; speedup vs baseline: 1.0484x; 1.0138x over previous
//
#include <hip/hip_runtime.h>
#include <math.h>

#define SEQ      8192
#define NTHREADS 512
#define NWAVES   8            // 512 / 64
#define VPT      16           // values per thread per row
#define F4PT     4            // float4 per thread per row

__device__ __forceinline__ float wave_sum(float x) {
    #pragma unroll
    for (int off = 32; off > 0; off >>= 1)
        x += __shfl_xor(x, off, 64);
    return x;
}

// One row per 512-thread block (8 waves). Payload = 16 floats/thread so true
// register demand (~40 VGPR) fits the 64-VGPR / 8-waves-per-SIMD budget with
// NO spill (round-1's VPT=32 under launch_bounds(256,8) spilled to AGPR+scratch:
// VGPR=32 arch + 12MB scratch writes, doubling VALU issue). Work independent of
// the reduction result (u *= 1/0.7, the t=7 e-domain conversion) is issued
// between the LDS write and the barrier to hide in the sync shadow.
__global__ __launch_bounds__(NTHREADS, 8) void normalizer_kernel(
        const float* __restrict__ score,
        const int*   __restrict__ mask,
        float*       __restrict__ out)
{
    const int row  = blockIdx.x;
    const int tid  = threadIdx.x;
    const int wid  = tid >> 6;
    const int lane = tid & 63;

    constexpr double L2E = 1.4426950408889634;               // log2(e)
    constexpr double TH7 = 4.0*0.7*0.7*0.7*0.7*0.7*0.7*0.7;  // theta at t=7 (0.32942 > 0.3)
    const float cu0 = (float)(L2E / 4.0);   // score -> u = score*log2e/theta0
    const float r07 = (float)(1.0 / 0.7);   // theta_t / theta_{t+1}
    const float ce  = (float)(TH7 / 0.3);   // u7 -> w-domain scale (for exp2)

    const float4* __restrict__ s4 = (const float4*)(score + (size_t)row * SEQ);
    const int4*   __restrict__ m4 = (const int4*)(mask  + (size_t)row * SEQ);

    // u_t = score * log2e / theta_t, masked -> -inf (exp2(-inf)=0 handles all)
    float u[VPT];
    int cnt = 0;
    #pragma unroll
    for (int j = 0; j < F4PT; ++j) {
        float4 s = s4[j * NTHREADS + tid];
        int4   m = m4[j * NTHREADS + tid];
        u[4*j+0] = m.x ? s.x * cu0 : -INFINITY;
        u[4*j+1] = m.y ? s.y * cu0 : -INFINITY;
        u[4*j+2] = m.z ? s.z * cu0 : -INFINITY;
        u[4*j+3] = m.w ? s.w * cu0 : -INFINITY;
        cnt += (m.x != 0) + (m.y != 0) + (m.z != 0) + (m.w != 0);
    }

    __shared__ float redc[NWAVES];
    __shared__ float red[2][NWAVES];   // double-buffered: one barrier per iteration

    #define BLOCK_SUM(b) (red[b][0] + red[b][1] + red[b][2] + red[b][3] + \
                          red[b][4] + red[b][5] + red[b][6] + red[b][7])

    // ---- fused: mask count + t=0 sum (NA = +inf at t=0, so no clamp, no k) ----
    float a0 = 0.f, a1 = 0.f;
    #pragma unroll
    for (int j = 0; j < VPT; j += 2) {
        a0 += __builtin_amdgcn_exp2f(u[j]);
        a1 += __builtin_amdgcn_exp2f(u[j+1]);
    }
    float pc = wave_sum((float)cnt);
    float ps = wave_sum(a0 + a1);
    if (lane == 0) { redc[wid] = pc; red[0][wid] = ps; }
    #pragma unroll
    for (int j = 0; j < VPT; ++j) u[j] *= r07;   // prep t=1 in sync shadow
    __syncthreads();
    const float k   = 0.1f * (redc[0] + redc[1] + redc[2] + redc[3] +
                              redc[4] + redc[5] + redc[6] + redc[7]);
    const float l2k = __builtin_amdgcn_logf(k);  // v_log_f32 = log2
    const float rk  = 1.0f / k;
    float s_ = BLOCK_SUM(0);
    // NAcp for iter t+1 = (log2 s_t - log2 k) * theta_t/theta_{t+1} = (..)*(1/0.7)
    float NAcp = (__builtin_amdgcn_logf(s_ + 1e-20f) - l2k) * r07;

    // ---- t = 1..6: identical bodies ----
    for (int t = 1; t < 7; ++t) {
        a0 = 0.f; a1 = 0.f;
        #pragma unroll
        for (int j = 0; j < VPT; j += 2) {
            a0 += __builtin_amdgcn_exp2f(fminf(u[j],   NAcp));
            a1 += __builtin_amdgcn_exp2f(fminf(u[j+1], NAcp));
        }
        float pa = wave_sum(a0 + a1);
        if (lane == 0) red[t & 1][wid] = pa;
        #pragma unroll
        for (int j = 0; j < VPT; ++j) u[j] *= r07;  // independent: sync shadow
        __syncthreads();
        s_ = BLOCK_SUM(t & 1);
        NAcp = (__builtin_amdgcn_logf(s_ + 1e-20f) - l2k) * r07;
    }

    // ---- t = 7: last exp step; convert u -> e = exp2(w) in the sync shadow ----
    {
        a0 = 0.f; a1 = 0.f;
        #pragma unroll
        for (int j = 0; j < VPT; j += 2) {
            a0 += __builtin_amdgcn_exp2f(fminf(u[j],   NAcp));
            a1 += __builtin_amdgcn_exp2f(fminf(u[j+1], NAcp));
        }
        float pa = wave_sum(a0 + a1);
        if (lane == 0) red[1][wid] = pa;           // 7 & 1
        #pragma unroll
        for (int j = 0; j < VPT; ++j)
            u[j] = __builtin_amdgcn_exp2f(u[j] * ce);   // e-domain, sync shadow
        __syncthreads();
        s_ = BLOCK_SUM(1);
    }
    // eNA = exp2(NA_7) = exp2((log2 s7 - log2 k) * theta7/0.3)
    float eNA = __builtin_amdgcn_exp2f((__builtin_amdgcn_logf(s_ + 1e-20f) - l2k) * ce);

    // ---- t = 8..19: theta = 0.3 clamped; s = sum(min(e, eNA)); eNA' = s/k ----
    for (int t = 8; t < 20; ++t) {
        a0 = 0.f; a1 = 0.f;
        #pragma unroll
        for (int j = 0; j < VPT; j += 2) {
            a0 += fminf(u[j],   eNA);
            a1 += fminf(u[j+1], eNA);
        }
        float pa = wave_sum(a0 + a1);
        if (lane == 0) red[t & 1][wid] = pa;
        __syncthreads();
        s_ = BLOCK_SUM(t & 1);
        eNA = (s_ + 1e-20f) * rk;
    }

    // gamma = min(e, eNA) / eNA.  Masked: e = 0 -> 0.
    const float ra = 1.0f / eNA;
    float4* __restrict__ o4 = (float4*)(out + (size_t)row * SEQ);
    #pragma unroll
    for (int j = 0; j < F4PT; ++j) {
        float4 g;
        g.x = fminf(u[4*j+0], eNA) * ra;
        g.y = fminf(u[4*j+1], eNA) * ra;
        g.z = fminf(u[4*j+2], eNA) * ra;
        g.w = fminf(u[4*j+3], eNA) * ra;
        o4[j * NTHREADS + tid] = g;
    }
}

extern "C" void kernel_launch(void* const* d_in, const int* in_sizes, int n_in,
                              void* d_out, int out_size, void* d_ws, size_t ws_size,
                              hipStream_t stream) {
    const float* score = (const float*)d_in[0];
    const int*   mask  = (const int*)d_in[1];
    float*       out   = (float*)d_out;
    const int rows = in_sizes[0] / SEQ;          // 4096
    normalizer_kernel<<<rows, NTHREADS, 0, stream>>>(score, mask, out);
}